// Round 5
// baseline (323.319 us; speedup 1.0000x reference)
//
#include <hip/hip_runtime.h>

#define Ecnt 512
#define Dd 64
#define Aa 8
#define Hh 256
#define Nn 16
#define Tt 128
#define NH 144            // 16 time outputs + 128 anchor outputs
#define SF2c 0.01f
#define SN2c 0.01f
#define NEGHALF_INV_L2 (-50.0f)   // -0.5 / 0.1^2

// ws layout (floats)
#define OFF_W1T 0                          // [Dd][Hh]
#define OFF_W2T (OFF_W1T + Dd * Hh)        // [Hh][Hh]
#define OFF_WHT (OFF_W2T + Hh * Hh)        // [Hh][NH]
#define OFF_BH  (OFF_WHT + Hh * NH)        // [NH]
#define OFF_TT  (OFF_BH + NH)              // [Ecnt][Nn]   per-example train times
#define OFF_KS  (OFF_TT + Ecnt * Nn)       // [Ecnt][Tt][Nn]  Ks
#define OFF_V   (OFF_KS + Ecnt * Tt * Nn)  // [Ecnt][Nn][Tt]  V = K^-1 Ks^T
#define WS_FLOATS (OFF_V + Ecnt * Nn * Tt)

__global__ void prep(const float* __restrict__ W1, const float* __restrict__ W2,
                     const float* __restrict__ Wt, const float* __restrict__ Wa,
                     const float* __restrict__ bt, const float* __restrict__ ba,
                     float* __restrict__ ws) {
    int id = blockIdx.x * blockDim.x + threadIdx.x;
    if (id < Dd * Hh) {
        int k = id >> 8, o = id & 255;
        ws[OFF_W1T + id] = W1[o * Dd + k];
    } else if (id < OFF_WHT) {
        int r = id - OFF_W2T; int k = r >> 8, o = r & 255;
        ws[id] = W2[o * Hh + k];
    } else if (id < OFF_BH) {
        int r = id - OFF_WHT; int k = r / NH, j = r % NH;
        ws[id] = (j < Nn) ? Wt[j * Hh + k] : Wa[(j - Nn) * Hh + k];
    } else if (id < OFF_TT) {
        int j = id - OFF_BH;
        ws[id] = (j < Nn) ? bt[j] : ba[j - Nn];
    }
}

// ---- k1: per-example MLP + Cholesky + solves + mu; dump tt/Ks/V to ws ----
__global__ __launch_bounds__(256, 2) void grp_solve(
    const float* __restrict__ x,
    const float* __restrict__ b1, const float* __restrict__ b2,
    const float* __restrict__ tarr, float* __restrict__ ws,
    float* __restrict__ out_mu)
{
    const int e   = blockIdx.x;
    const int tid = threadIdx.x;

    __shared__ float xs[Dd];
    __shared__ float h1s[Hh];
    __shared__ float h2s[Hh];
    __shared__ float tt[Nn];
    __shared__ float tq[Tt];
    __shared__ float yy[Aa][Nn];
    __shared__ float Km[Nn][Nn + 1];
    __shared__ float Lm[Nn][Nn + 1];
    __shared__ float tmpv[Nn];
    __shared__ __align__(16) float Ks[Tt][Nn];   // Ks[q][i]
    __shared__ __align__(16) float V[Nn][Tt];    // V[i][q]
    __shared__ float alpha[Aa][Nn];

    if (tid < Dd) xs[tid] = x[e * Dd + tid];
    if (tid < Tt) tq[tid] = tarr[tid];
    __syncthreads();

    const float* __restrict__ W1T = ws + OFF_W1T;
    const float* __restrict__ W2T = ws + OFF_W2T;
    const float* __restrict__ WHT = ws + OFF_WHT;
    const float* __restrict__ BH  = ws + OFF_BH;

    // MLP (coalesced weight loads, LDS-broadcast activations)
    {
        float acc = b1[tid];
        #pragma unroll 8
        for (int k = 0; k < Dd; ++k) acc += W1T[k * Hh + tid] * xs[k];
        h1s[tid] = tanhf(acc);
    }
    __syncthreads();
    {
        float acc = b2[tid];
        #pragma unroll 8
        for (int k = 0; k < Hh; ++k) acc += W2T[k * Hh + tid] * h1s[k];
        h2s[tid] = tanhf(acc);
    }
    __syncthreads();
    if (tid < NH) {
        float acc = BH[tid];
        #pragma unroll 8
        for (int k = 0; k < Hh; ++k) acc += WHT[k * NH + tid] * h2s[k];
        if (tid < Nn) tt[tid] = acc;
        else { int r = tid - Nn; yy[r >> 4][r & 15] = acc; }
    }
    __syncthreads();

    // K and Ks
    {
        int i = tid >> 4, j = tid & 15;
        float d = tt[i] - tt[j];
        Km[i][j] = SF2c * __expf(NEGHALF_INV_L2 * d * d) + (i == j ? SN2c : 0.f);
    }
    #pragma unroll
    for (int r = 0; r < 8; ++r) {
        int idx = tid + r * 256;
        int q = idx >> 4, i = idx & 15;
        float d = tq[q] - tt[i];
        Ks[q][i] = SF2c * __expf(NEGHALF_INV_L2 * d * d);
    }
    __syncthreads();

    // Cholesky (rolled — small code, latency-bound anyway)
    for (int j = 0; j < Nn; ++j) {
        if (tid >= j && tid < Nn) {
            float s = Km[tid][j];
            for (int k = 0; k < j; ++k) s -= Lm[tid][k] * Lm[j][k];
            tmpv[tid] = s;
        }
        __syncthreads();
        if (tid >= j && tid < Nn) {
            float dj = sqrtf(tmpv[j]);
            Lm[tid][j] = (tid == j) ? dj : tmpv[tid] / dj;
        }
        __syncthreads();
    }

    // batched triangular solves: 128 V columns + 8 alphas
    if (tid < Tt + Aa) {
        float bz[Nn];
        if (tid < Tt) {
            float tqv = tq[tid];
            #pragma unroll
            for (int i = 0; i < Nn; ++i) {
                float d = tqv - tt[i];
                bz[i] = SF2c * __expf(NEGHALF_INV_L2 * d * d);
            }
        } else {
            int a = tid - Tt;
            #pragma unroll
            for (int i = 0; i < Nn; ++i) bz[i] = yy[a][i];
        }
        #pragma unroll
        for (int i = 0; i < Nn; ++i) {
            float s = bz[i];
            for (int k = 0; k < i; ++k) s -= Lm[i][k] * bz[k];
            bz[i] = s / Lm[i][i];
        }
        #pragma unroll
        for (int i = Nn - 1; i >= 0; --i) {
            float s = bz[i];
            for (int k = i + 1; k < Nn; ++k) s -= Lm[k][i] * bz[k];
            bz[i] = s / Lm[i][i];
        }
        if (tid < Tt) {
            #pragma unroll
            for (int i = 0; i < Nn; ++i) V[i][tid] = bz[i];
        } else {
            int a = tid - Tt;
            #pragma unroll
            for (int i = 0; i < Nn; ++i) alpha[a][i] = bz[i];
        }
    }
    __syncthreads();

    // mu
    if (tid < Tt) {
        float ks[Nn];
        #pragma unroll
        for (int i = 0; i < Nn; ++i) ks[i] = Ks[tid][i];
        size_t mb = (size_t)e * (Aa * Tt) + tid;
        #pragma unroll
        for (int a = 0; a < Aa; ++a) {
            float m = 0.f;
            #pragma unroll
            for (int i = 0; i < Nn; ++i) m += ks[i] * alpha[a][i];
            out_mu[mb + (size_t)a * Tt] = m;
        }
    }

    // dump tt, Ks, V for the cov kernel
    if (tid < Nn) ws[OFF_TT + e * Nn + tid] = tt[tid];
    {
        float4* dK = (float4*)(ws + OFF_KS + (size_t)e * (Tt * Nn));
        const float4* sK = (const float4*)&Ks[0][0];
        dK[tid] = sK[tid];
        dK[tid + 256] = sK[tid + 256];
        float4* dV = (float4*)(ws + OFF_V + (size_t)e * (Nn * Tt));
        const float4* sV = (const float4*)&V[0][0];
        dV[tid] = sV[tid];
        dV[tid + 256] = sV[tid + 256];
    }
}

// ---- k2: cov = Kss - Ks.V, written 8x; block = (e, 32-row chunk) ----
__global__ __launch_bounds__(256, 4) void grp_cov(
    const float* __restrict__ ws, const float* __restrict__ tarr,
    float* __restrict__ out_cov)
{
    const int b  = blockIdx.x;
    const int e  = b >> 2;
    const int ch = b & 3;
    const int tid = threadIdx.x;

    __shared__ __align__(16) float Vs[Nn][Tt];      // 8 KB
    __shared__ __align__(16) float Ksl[32][Nn];     // 2 KB: chunk's Ks rows
    __shared__ float tqs[Tt];

    {
        const float4* sV = (const float4*)(ws + OFF_V + (size_t)e * (Nn * Tt));
        float4* dV = (float4*)&Vs[0][0];
        dV[tid] = sV[tid];
        dV[tid + 256] = sV[tid + 256];
        if (tid < 128) {
            const float4* sK = (const float4*)(ws + OFF_KS + (size_t)e * (Tt * Nn) + (size_t)ch * 32 * Nn);
            ((float4*)&Ksl[0][0])[tid] = sK[tid];
        }
        if (tid < Tt) tqs[tid] = tarr[tid];
    }
    __syncthreads();

    const int q4 = (tid & 31) * 4;
    const int pr = tid >> 5;                    // 0..7
    float vq[Nn][4];
    #pragma unroll
    for (int i = 0; i < Nn; ++i) {
        float4 vv = *(const float4*)&Vs[i][q4];
        vq[i][0] = vv.x; vq[i][1] = vv.y; vq[i][2] = vv.z; vq[i][3] = vv.w;
    }
    const float tqq0 = tqs[q4 + 0], tqq1 = tqs[q4 + 1], tqq2 = tqs[q4 + 2], tqq3 = tqs[q4 + 3];
    float* covb = out_cov + (size_t)e * (Aa * Tt * Tt);

    #pragma unroll
    for (int pp = 0; pp < 4; ++pp) {
        const int lp = pr * 4 + pp;             // 0..31
        const int p  = ch * 32 + lp;
        const float tqp = tqs[p];
        float d0 = tqp - tqq0, d1 = tqp - tqq1, d2 = tqp - tqq2, d3 = tqp - tqq3;
        float a0 = SF2c * __expf(NEGHALF_INV_L2 * d0 * d0);
        float a1 = SF2c * __expf(NEGHALF_INV_L2 * d1 * d1);
        float a2 = SF2c * __expf(NEGHALF_INV_L2 * d2 * d2);
        float a3 = SF2c * __expf(NEGHALF_INV_L2 * d3 * d3);
        #pragma unroll
        for (int i = 0; i < Nn; ++i) {
            float ks = Ksl[lp][i];              // broadcast within 32-lane group
            a0 -= ks * vq[i][0];
            a1 -= ks * vq[i][1];
            a2 -= ks * vq[i][2];
            a3 -= ks * vq[i][3];
        }
        float4 pk; pk.x = a0; pk.y = a1; pk.z = a2; pk.w = a3;
        const size_t ro = (size_t)p * Tt + q4;
        #pragma unroll
        for (int a = 0; a < Aa; ++a) {
            *(float4*)(covb + (size_t)a * (Tt * Tt) + ro) = pk;
        }
    }
}

extern "C" void kernel_launch(void* const* d_in, const int* in_sizes, int n_in,
                              void* d_out, int out_size, void* d_ws, size_t ws_size,
                              hipStream_t stream) {
    (void)in_sizes; (void)n_in; (void)out_size; (void)ws_size;
    const float* x  = (const float*)d_in[0];
    // d_in[1] (a) and d_in[2] (da) unused by the reference
    const float* W1 = (const float*)d_in[3];
    const float* b1 = (const float*)d_in[4];
    const float* W2 = (const float*)d_in[5];
    const float* b2 = (const float*)d_in[6];
    const float* Wt = (const float*)d_in[7];
    const float* bt = (const float*)d_in[8];
    const float* Wa = (const float*)d_in[9];
    const float* ba = (const float*)d_in[10];
    const float* ta = (const float*)d_in[11];
    float* mu  = (float*)d_out;
    float* cov = mu + (size_t)Ecnt * Aa * Tt;
    float* wsf = (float*)d_ws;

    prep<<<(OFF_TT + 255) / 256, 256, 0, stream>>>(W1, W2, Wt, Wa, bt, ba, wsf);
    grp_solve<<<Ecnt, 256, 0, stream>>>(x, b1, b2, ta, wsf, mu);
    grp_cov<<<Ecnt * 4, 256, 0, stream>>>(wsf, ta, cov);
}